// Round 8
// baseline (669.494 us; speedup 1.0000x reference)
//
#include <hip/hip_runtime.h>

// DissipativeRINN — fp16 MFMA, block-cooperative K-reduction, 2 blocks/CU.
// 512 blocks x 4 waves (256 thr); block = 4 batch rows (M-rows 0-3 of 16-tile).
// Wave w owns w-cols 32w..32w+31 (2 N-tiles): 8 MFMA per fixed-point iter,
// as two 2-deep half-chains + VALU add. w exchanged via double-buffered
// XOR-swizzled LDS tile [16][128] f16; one __syncthreads per iteration.
// 2 independent blocks per CU hide each other's latency/barrier stalls.

typedef _Float16 f16x8 __attribute__((ext_vector_type(8)));
typedef float f32x4 __attribute__((ext_vector_type(4)));

constexpr int B_TOT   = 2048;
constexpr int T_STEPS = 32;
constexpr int IN_D    = 16;
constexpr int ST_D    = 16;
constexpr int NL_D    = 128;
constexpr int OUT_D   = 8;
constexpr int H_D     = 64;
constexpr int OUT_C   = 17;
constexpr float DT_F  = 0.01f;
constexpr float SC    = 2.8853900817779268f;   // 2*log2(e)

constexpr int RB      = 4;                     // batch rows per block
constexpr int WBUF_SZ = 4096;                  // [16 rows][128 k] f16
constexpr int XY_OFF  = 2 * WBUF_SZ;           // xy tile [16][32] f16 (1 KB)
constexpr int LDS_SZ  = XY_OFF + 1024;

__global__ __launch_bounds__(256, 2) void rinn_fpi(
    const float* __restrict__ obs, const float* __restrict__ x0,
    const float* __restrict__ A_T, const float* __restrict__ Bw_T,
    const float* __restrict__ By_T, const float* __restrict__ Cv_T,
    const float* __restrict__ Dvw_T, const float* __restrict__ Dvy_T,
    const float* __restrict__ Cu_T, const float* __restrict__ Duw_T,
    const float* __restrict__ Duy_T, float* __restrict__ out)
{
    __shared__ __align__(16) char lds[LDS_SZ];
    const int tid  = threadIdx.x;
    const int wid  = tid >> 6;                 // 0..3
    const int lane = tid & 63;
    const int g    = lane >> 4;
    const int c16  = lane & 15;
    const int b0   = blockIdx.x * RB;
    const f32x4 z4 = {0.f, 0.f, 0.f, 0.f};

    // ---- resident B fragments: 2 N-tiles per wave ----
    f16x8 bD[4][2];                            // Dvw k-chunks x N-tiles (x SC)
#pragma unroll
    for (int s = 0; s < 4; ++s)
#pragma unroll
        for (int n = 0; n < 2; ++n) {
            const int col = 32 * wid + 16 * n + c16;
            f16x8 h;
#pragma unroll
            for (int j = 0; j < 8; ++j)
                h[j] = (_Float16)(SC * Dvw_T[(s * 32 + g * 8 + j) * NL_D + col]);
            bD[s][n] = h;
        }
    f16x8 bBias[2];                            // [Cv;Dvy] K=32 (x SC)
#pragma unroll
    for (int n = 0; n < 2; ++n) {
        const int col = 32 * wid + 16 * n + c16;
        f16x8 h;
#pragma unroll
        for (int j = 0; j < 8; ++j) {
            int k = g * 8 + j;
            float v = (k < 16) ? Cv_T[k * NL_D + col] : Dvy_T[(k - 16) * NL_D + col];
            h[j] = (_Float16)(SC * v);
        }
        bBias[n] = h;
    }
    f16x8 bKU[5];                              // wave0: [A;By;Bw], wave1: [Cu;Duy;Duw]
    if (wid == 0) {
        f16x8 h;
#pragma unroll
        for (int j = 0; j < 8; ++j) {
            int k = g * 8 + j;
            h[j] = (_Float16)((k < 16) ? A_T[k * ST_D + c16] : By_T[(k - 16) * ST_D + c16]);
        }
        bKU[0] = h;
#pragma unroll
        for (int s = 0; s < 4; ++s) {
            f16x8 h2;
#pragma unroll
            for (int j = 0; j < 8; ++j)
                h2[j] = (_Float16)Bw_T[(s * 32 + g * 8 + j) * ST_D + c16];
            bKU[1 + s] = h2;
        }
    } else if (wid == 1) {
        f16x8 h;
#pragma unroll
        for (int j = 0; j < 8; ++j) {
            int k = g * 8 + j;
            float v = (c16 < OUT_D)
                ? ((k < 16) ? Cu_T[k * OUT_D + c16] : Duy_T[(k - 16) * OUT_D + c16]) : 0.f;
            h[j] = (_Float16)v;
        }
        bKU[0] = h;
#pragma unroll
        for (int s = 0; s < 4; ++s) {
            f16x8 h2;
#pragma unroll
            for (int j = 0; j < 8; ++j)
                h2[j] = (_Float16)((c16 < OUT_D) ? Duw_T[(s * 32 + g * 8 + j) * OUT_D + c16] : 0.f);
            bKU[1 + s] = h2;
        }
    }

    // ---- zero all LDS (pad rows 4-15 must stay zero forever) ----
    for (int off = tid * 16; off < LDS_SZ; off += 256 * 16)
        *(f32x4*)(lds + off) = z4;
    __syncthreads();

    // ---- x state: wave 0, g==0 lanes hold rows j=0..3, col c16 ----
    f32x4 xb = z4, k1 = z4, k2 = z4, k3 = z4, k4 = z4;
    if (wid == 0 && g == 0) {
#pragma unroll
        for (int j = 0; j < 4; ++j) {
            xb[j] = x0[(b0 + j) * ST_D + c16];
            *(_Float16*)(lds + XY_OFF + j * 64 + ((2 * c16) ^ ((j & 3) << 4))) =
                (_Float16)xb[j];
        }
    }

    auto ld_xy = [&]() -> f16x8 {
        return __builtin_bit_cast(f16x8,
            *(const f32x4*)(lds + XY_OFF + c16 * 64 + ((g * 16) ^ ((c16 & 3) << 4))));
    };
    auto ldA = [&](int buf, int s) -> f16x8 {
        return __builtin_bit_cast(f16x8,
            *(const f32x4*)(lds + buf * WBUF_SZ + c16 * 256 +
                            ((s * 64 + g * 16) ^ ((c16 & 7) << 4))));
    };

    int cur = 0;

#pragma unroll 1
    for (int t = 0; t < T_STEPS; ++t) {
        // w_init = 0: zero rows 0-3 of w[cur] (1 KB, 4B/thread)
        *(int*)(lds + cur * WBUF_SZ + tid * 4) = 0;
        // y rows 0-3 for this step (wave 2)
        if (wid == 2 && g == 0) {
#pragma unroll
            for (int j = 0; j < 4; ++j) {
                float yv = obs[((b0 + j) * T_STEPS + t) * IN_D + c16];
                *(_Float16*)(lds + XY_OFF + j * 64 + ((32 + 2 * c16) ^ ((j & 3) << 4))) =
                    (_Float16)yv;
            }
        }
        __syncthreads();

#pragma unroll 1
        for (int st = 0; st < 4; ++st) {
            // bias for this stage's x (both N-tiles)
            f32x4 biasAcc[2];
            {
                f16x8 aXY = ld_xy();
#pragma unroll
                for (int n = 0; n < 2; ++n)
                    biasAcc[n] = __builtin_amdgcn_mfma_f32_16x16x32_f16(aXY, bBias[n], z4, 0, 0, 0);
            }
            const int niter = st ? 5 : 30;
#pragma unroll 1
            for (int it = 0; it < niter; ++it) {
                f16x8 a0 = ldA(cur, 0), a1 = ldA(cur, 1), a2 = ldA(cur, 2), a3 = ldA(cur, 3);
                f32x4 tt[2];
#pragma unroll
                for (int n = 0; n < 2; ++n) {
                    // two 2-deep half-chains (shorter dependency) + VALU add
                    f32x4 h0 = __builtin_amdgcn_mfma_f32_16x16x32_f16(a0, bD[0][n], biasAcc[n], 0, 0, 0);
                    h0 = __builtin_amdgcn_mfma_f32_16x16x32_f16(a1, bD[1][n], h0, 0, 0, 0);
                    f32x4 h1 = __builtin_amdgcn_mfma_f32_16x16x32_f16(a2, bD[2][n], z4, 0, 0, 0);
                    h1 = __builtin_amdgcn_mfma_f32_16x16x32_f16(a3, bD[3][n], h1, 0, 0, 0);
                    tt[n] = h0 + h1;
                }
                if (g == 0) {                  // rows 0-3 real; write w[nxt]
#pragma unroll
                    for (int n = 0; n < 2; ++n) {
                        const int col = 32 * wid + 16 * n + c16;
#pragma unroll
                        for (int j = 0; j < 4; ++j) {
                            float e = __builtin_amdgcn_exp2f(tt[n][j]);   // e^{2a}
                            float v = fmaf(-2.0f, __builtin_amdgcn_rcpf(1.0f + e), 1.0f);
                            *(_Float16*)(lds + (cur ^ 1) * WBUF_SZ + j * 256 +
                                         ((2 * col) ^ ((j & 7) << 4))) = (_Float16)v;
                        }
                    }
                }
                __syncthreads();
                cur ^= 1;
            }
            // ---- epilogue: k (wave 0) / u (wave 1), K=160 over [xy | w] ----
            f32x4 acc = z4;
            if (wid < 2) {
                f16x8 aXY = ld_xy();
                f16x8 a0 = ldA(cur, 0), a1 = ldA(cur, 1), a2 = ldA(cur, 2), a3 = ldA(cur, 3);
                acc = __builtin_amdgcn_mfma_f32_16x16x32_f16(aXY, bKU[0], z4, 0, 0, 0);
                acc = __builtin_amdgcn_mfma_f32_16x16x32_f16(a0, bKU[1], acc, 0, 0, 0);
                acc = __builtin_amdgcn_mfma_f32_16x16x32_f16(a1, bKU[2], acc, 0, 0, 0);
                acc = __builtin_amdgcn_mfma_f32_16x16x32_f16(a2, bKU[3], acc, 0, 0, 0);
                acc = __builtin_amdgcn_mfma_f32_16x16x32_f16(a3, bKU[4], acc, 0, 0, 0);
            }
            __syncthreads();                   // xy reads done before x update
            if (wid == 1 && st == 0 && c16 < OUT_D && g == 0) {
#pragma unroll
                for (int j = 0; j < 4; ++j)
                    out[((b0 + j) * T_STEPS + t) * OUT_C + c16] = acc[j];
            }
            if (wid == 0) {
                float xn[4];
                if (st == 0) {
                    k1 = acc;
#pragma unroll
                    for (int j = 0; j < 4; ++j) xn[j] = fmaf(0.5f * DT_F, k1[j], xb[j]);
                } else if (st == 1) {
                    k2 = acc;
#pragma unroll
                    for (int j = 0; j < 4; ++j) xn[j] = fmaf(0.5f * DT_F, k2[j], xb[j]);
                } else if (st == 2) {
                    k3 = acc;
#pragma unroll
                    for (int j = 0; j < 4; ++j) xn[j] = fmaf(DT_F, k3[j], xb[j]);
                } else {
                    k4 = acc;
#pragma unroll
                    for (int j = 0; j < 4; ++j) {
                        xb[j] = fmaf(DT_F / 6.0f,
                                     k1[j] + 2.0f * k2[j] + 2.0f * k3[j] + k4[j], xb[j]);
                        xn[j] = xb[j];
                    }
                }
                if (g == 0) {
#pragma unroll
                    for (int j = 0; j < 4; ++j)
                        *(_Float16*)(lds + XY_OFF + j * 64 +
                                     ((2 * c16) ^ ((j & 3) << 4))) = (_Float16)xn[j];
                }
            }
            __syncthreads();                   // new x visible for next bias
        }
    }
}

// ---- value baseline MLP + log_std broadcast (unchanged) ----
__device__ __forceinline__ float fast_tanh(float a) {
    float e = __expf(2.0f * a);
    return 1.0f - 2.0f / (e + 1.0f);
}

__global__ __launch_bounds__(256) void mlp_kernel(
    const float* __restrict__ obs, const float* __restrict__ log_stds,
    const float* __restrict__ W1, const float* __restrict__ b1,
    const float* __restrict__ W2, const float* __restrict__ b2,
    const float* __restrict__ W3, const float* __restrict__ b3,
    float* __restrict__ out) {
    __shared__ float sW1[IN_D * H_D];
    __shared__ float sW2[H_D * H_D];
    __shared__ float sb1[H_D], sb2[H_D], sW3[H_D], sls[OUT_D];
    __shared__ float sb3;
    const int tid = threadIdx.x;
    for (int i = tid; i < IN_D * H_D; i += 256) sW1[i] = W1[i];
    for (int i = tid; i < H_D * H_D; i += 256) sW2[i] = W2[i];
    if (tid < H_D) { sb1[tid] = b1[tid]; sb2[tid] = b2[tid]; sW3[tid] = W3[tid]; }
    if (tid < OUT_D) sls[tid] = log_stds[tid];
    if (tid == 0) sb3 = b3[0];
    __syncthreads();

    const int bt = blockIdx.x * 256 + tid;
    if (bt >= B_TOT * T_STEPS) return;

    float o[IN_D];
#pragma unroll
    for (int i = 0; i < IN_D; ++i) o[i] = obs[bt * IN_D + i];

    float h1[H_D];
#pragma unroll
    for (int h = 0; h < H_D; ++h) {
        float a = sb1[h];
#pragma unroll
        for (int i = 0; i < IN_D; ++i) a = fmaf(o[i], sW1[i * H_D + h], a);
        h1[h] = fast_tanh(a);
    }
    float v = sb3;
#pragma unroll
    for (int h = 0; h < H_D; ++h) {
        float a = sb2[h];
#pragma unroll
        for (int i = 0; i < H_D; ++i) a = fmaf(h1[i], sW2[i * H_D + h], a);
        v = fmaf(fast_tanh(a), sW3[h], v);
    }

    float* o17 = out + bt * OUT_C;
#pragma unroll
    for (int q = 0; q < OUT_D; ++q) o17[OUT_D + q] = sls[q];
    o17[16] = v;
}

extern "C" void kernel_launch(void* const* d_in, const int* in_sizes, int n_in,
                              void* d_out, int out_size, void* d_ws, size_t ws_size,
                              hipStream_t stream) {
    const float* obs      = (const float*)d_in[0];
    const float* x0       = (const float*)d_in[1];
    const float* A_T      = (const float*)d_in[2];
    const float* Bw_T     = (const float*)d_in[3];
    const float* By_T     = (const float*)d_in[4];
    const float* Cv_T     = (const float*)d_in[5];
    const float* Dvw_T    = (const float*)d_in[6];
    const float* Dvy_T    = (const float*)d_in[7];
    const float* Cu_T     = (const float*)d_in[8];
    const float* Duw_T    = (const float*)d_in[9];
    const float* Duy_T    = (const float*)d_in[10];
    const float* log_stds = (const float*)d_in[11];
    const float* W1       = (const float*)d_in[12];
    const float* b1       = (const float*)d_in[13];
    const float* W2       = (const float*)d_in[14];
    const float* b2       = (const float*)d_in[15];
    const float* W3       = (const float*)d_in[16];
    const float* b3       = (const float*)d_in[17];
    float* out = (float*)d_out;

    rinn_fpi<<<dim3(B_TOT / RB), dim3(256), 0, stream>>>(
        obs, x0, A_T, Bw_T, By_T, Cv_T, Dvw_T, Dvy_T, Cu_T, Duw_T, Duy_T, out);
    mlp_kernel<<<dim3((B_TOT * T_STEPS + 255) / 256), dim3(256), 0, stream>>>(
        obs, log_stds, W1, b1, W2, b2, W3, b3, out);
}

// Round 9
// 520.953 us; speedup vs baseline: 1.2851x; 1.2851x over previous
//
#include <hip/hip_runtime.h>

// DissipativeRINN — fp16 MFMA, block-cooperative K-reduction (R7 structure).
// 256 blocks x 8 waves (512 thr); block = 8 batch rows (M-rows 0-7 of 16-tile).
// Wave w owns w-cols 16w..16w+15: 4 MFMA/iter as two 2-deep half-chains.
// w exchanged via double-buffered XOR-swizzled LDS tile [16][128] f16
// (full-row swizzle ^(row<<4): conflict-free ds_read_b128); one barrier/iter.
// tanh computed branchless on all 64 lanes; writes guarded to real rows.

typedef _Float16 f16x8 __attribute__((ext_vector_type(8)));
typedef float f32x4 __attribute__((ext_vector_type(4)));

constexpr int B_TOT   = 2048;
constexpr int T_STEPS = 32;
constexpr int IN_D    = 16;
constexpr int ST_D    = 16;
constexpr int NL_D    = 128;
constexpr int OUT_D   = 8;
constexpr int H_D     = 64;
constexpr int OUT_C   = 17;
constexpr float DT_F  = 0.01f;
constexpr float SC    = 2.8853900817779268f;   // 2*log2(e)

constexpr int RB      = 8;                     // batch rows per block
constexpr int WBUF_SZ = 4096;                  // [16 rows][128 k] f16
constexpr int XY_OFF  = 2 * WBUF_SZ;           // xy tile [16][32] f16 (1 KB)
constexpr int LDS_SZ  = XY_OFF + 1024;

__global__ __launch_bounds__(512, 1) void rinn_fpi(
    const float* __restrict__ obs, const float* __restrict__ x0,
    const float* __restrict__ A_T, const float* __restrict__ Bw_T,
    const float* __restrict__ By_T, const float* __restrict__ Cv_T,
    const float* __restrict__ Dvw_T, const float* __restrict__ Dvy_T,
    const float* __restrict__ Cu_T, const float* __restrict__ Duw_T,
    const float* __restrict__ Duy_T, float* __restrict__ out)
{
    __shared__ __align__(16) char lds[LDS_SZ];
    const int tid  = threadIdx.x;
    const int wid  = tid >> 6;                 // N-tile owned by this wave
    const int lane = tid & 63;
    const int g    = lane >> 4;
    const int c16  = lane & 15;
    const int b0   = blockIdx.x * RB;
    const int col  = 16 * wid + c16;           // this wave's w-column
    const f32x4 z4 = {0.f, 0.f, 0.f, 0.f};

    // ---- resident B fragments ----
    f16x8 bD[4];                               // Dvw k-chunks for N-tile wid (x SC)
#pragma unroll
    for (int s = 0; s < 4; ++s) {
        f16x8 h;
#pragma unroll
        for (int j = 0; j < 8; ++j)
            h[j] = (_Float16)(SC * Dvw_T[(s * 32 + g * 8 + j) * NL_D + col]);
        bD[s] = h;
    }
    f16x8 bBias;                               // [Cv;Dvy] K=32 (x SC)
    {
        f16x8 h;
#pragma unroll
        for (int j = 0; j < 8; ++j) {
            int k = g * 8 + j;
            float v = (k < 16) ? Cv_T[k * NL_D + col] : Dvy_T[(k - 16) * NL_D + col];
            h[j] = (_Float16)(SC * v);
        }
        bBias = h;
    }
    f16x8 bKU[5];                              // wave0: [A;By;Bw], wave1: [Cu;Duy;Duw]
    if (wid == 0) {
        f16x8 h;
#pragma unroll
        for (int j = 0; j < 8; ++j) {
            int k = g * 8 + j;
            h[j] = (_Float16)((k < 16) ? A_T[k * ST_D + c16] : By_T[(k - 16) * ST_D + c16]);
        }
        bKU[0] = h;
#pragma unroll
        for (int s = 0; s < 4; ++s) {
            f16x8 h2;
#pragma unroll
            for (int j = 0; j < 8; ++j)
                h2[j] = (_Float16)Bw_T[(s * 32 + g * 8 + j) * ST_D + c16];
            bKU[1 + s] = h2;
        }
    } else if (wid == 1) {
        f16x8 h;
#pragma unroll
        for (int j = 0; j < 8; ++j) {
            int k = g * 8 + j;
            float v = (c16 < OUT_D)
                ? ((k < 16) ? Cu_T[k * OUT_D + c16] : Duy_T[(k - 16) * OUT_D + c16]) : 0.f;
            h[j] = (_Float16)v;
        }
        bKU[0] = h;
#pragma unroll
        for (int s = 0; s < 4; ++s) {
            f16x8 h2;
#pragma unroll
            for (int j = 0; j < 8; ++j)
                h2[j] = (_Float16)((c16 < OUT_D) ? Duw_T[(s * 32 + g * 8 + j) * OUT_D + c16] : 0.f);
            bKU[1 + s] = h2;
        }
    }

    // ---- zero all LDS (pad rows 8-15 must stay zero forever) ----
    for (int off = tid * 16; off < LDS_SZ; off += 512 * 16)
        *(f32x4*)(lds + off) = z4;
    __syncthreads();

    // ---- x state: wave 0 lanes g<2 hold rows 4g+j, col c16 ----
    f32x4 xb = z4, k1 = z4, k2 = z4, k3 = z4, k4 = z4;
    if (wid == 0 && g < 2) {
#pragma unroll
        for (int j = 0; j < 4; ++j) {
            int row = 4 * g + j;
            xb[j] = x0[(b0 + row) * ST_D + c16];
            *(_Float16*)(lds + XY_OFF + row * 64 + ((2 * c16) ^ ((row & 3) << 4))) =
                (_Float16)xb[j];
        }
    }

    auto ld_xy = [&]() -> f16x8 {
        return __builtin_bit_cast(f16x8,
            *(const f32x4*)(lds + XY_OFF + c16 * 64 + ((g * 16) ^ ((c16 & 3) << 4))));
    };
    // full-row XOR swizzle: slot = (4s+g) ^ c16 — bijective per (s,g) over the
    // 16 A-rows -> conflict-free b128 reads. Identical bytes to the old
    // (c16&7) form for real rows 0-7; pad rows 8-15 are all-zero anyway.
    auto ldA = [&](int buf, int s) -> f16x8 {
        return __builtin_bit_cast(f16x8,
            *(const f32x4*)(lds + buf * WBUF_SZ + c16 * 256 +
                            ((s * 64 + g * 16) ^ (c16 << 4))));
    };

    int cur = 0;

#pragma unroll 1
    for (int t = 0; t < T_STEPS; ++t) {
        // w_init = 0: zero rows 0-7 of w[cur] (2 KB, 4B/thread)
        *(int*)(lds + cur * WBUF_SZ + tid * 4) = 0;
        // y rows 0-7 for this step (wave 2)
        if (wid == 2 && g < 2) {
#pragma unroll
            for (int j = 0; j < 4; ++j) {
                int row = 4 * g + j;
                float yv = obs[((b0 + row) * T_STEPS + t) * IN_D + c16];
                *(_Float16*)(lds + XY_OFF + row * 64 + ((32 + 2 * c16) ^ ((row & 3) << 4))) =
                    (_Float16)yv;
            }
        }
        __syncthreads();

#pragma unroll 1
        for (int st = 0; st < 4; ++st) {
            // bias for this stage's x
            f32x4 biasAcc;
            {
                f16x8 aXY = ld_xy();
                biasAcc = __builtin_amdgcn_mfma_f32_16x16x32_f16(aXY, bBias, z4, 0, 0, 0);
            }
            const int niter = st ? 5 : 30;
#pragma unroll 1
            for (int it = 0; it < niter; ++it) {
                f16x8 a0 = ldA(cur, 0), a1 = ldA(cur, 1), a2 = ldA(cur, 2), a3 = ldA(cur, 3);
                // two 2-deep half-chains + VALU add (shorter dep latency)
                f32x4 h0 = __builtin_amdgcn_mfma_f32_16x16x32_f16(a0, bD[0], biasAcc, 0, 0, 0);
                h0 = __builtin_amdgcn_mfma_f32_16x16x32_f16(a1, bD[1], h0, 0, 0, 0);
                f32x4 h1 = __builtin_amdgcn_mfma_f32_16x16x32_f16(a2, bD[2], z4, 0, 0, 0);
                h1 = __builtin_amdgcn_mfma_f32_16x16x32_f16(a3, bD[3], h1, 0, 0, 0);
                f32x4 tt = h0 + h1;
                // branchless tanh on all lanes (pad rows: bias 0, w 0 -> v 0)
                float v0 = fmaf(-2.0f, __builtin_amdgcn_rcpf(1.0f + __builtin_amdgcn_exp2f(tt[0])), 1.0f);
                float v1 = fmaf(-2.0f, __builtin_amdgcn_rcpf(1.0f + __builtin_amdgcn_exp2f(tt[1])), 1.0f);
                float v2 = fmaf(-2.0f, __builtin_amdgcn_rcpf(1.0f + __builtin_amdgcn_exp2f(tt[2])), 1.0f);
                float v3 = fmaf(-2.0f, __builtin_amdgcn_rcpf(1.0f + __builtin_amdgcn_exp2f(tt[3])), 1.0f);
                if (g < 2) {                   // rows 0-7 real; write w[nxt]
                    char* wb = lds + (cur ^ 1) * WBUF_SZ;
                    const int r0 = 4 * g;
                    *(_Float16*)(wb + (r0 + 0) * 256 + ((2 * col) ^ ((r0 + 0) << 4))) = (_Float16)v0;
                    *(_Float16*)(wb + (r0 + 1) * 256 + ((2 * col) ^ ((r0 + 1) << 4))) = (_Float16)v1;
                    *(_Float16*)(wb + (r0 + 2) * 256 + ((2 * col) ^ ((r0 + 2) << 4))) = (_Float16)v2;
                    *(_Float16*)(wb + (r0 + 3) * 256 + ((2 * col) ^ ((r0 + 3) << 4))) = (_Float16)v3;
                }
                __syncthreads();
                cur ^= 1;
            }
            // ---- epilogue: k (wave 0) / u (wave 1), K=160 over [xy | w] ----
            f32x4 acc = z4;
            if (wid < 2) {
                f16x8 aXY = ld_xy();
                f16x8 a0 = ldA(cur, 0), a1 = ldA(cur, 1), a2 = ldA(cur, 2), a3 = ldA(cur, 3);
                f32x4 e0 = __builtin_amdgcn_mfma_f32_16x16x32_f16(aXY, bKU[0], z4, 0, 0, 0);
                e0 = __builtin_amdgcn_mfma_f32_16x16x32_f16(a0, bKU[1], e0, 0, 0, 0);
                e0 = __builtin_amdgcn_mfma_f32_16x16x32_f16(a1, bKU[2], e0, 0, 0, 0);
                f32x4 e1 = __builtin_amdgcn_mfma_f32_16x16x32_f16(a2, bKU[3], z4, 0, 0, 0);
                e1 = __builtin_amdgcn_mfma_f32_16x16x32_f16(a3, bKU[4], e1, 0, 0, 0);
                acc = e0 + e1;
            }
            __syncthreads();                   // xy reads done before x update
            if (wid == 1 && st == 0 && c16 < OUT_D && g < 2) {
#pragma unroll
                for (int j = 0; j < 4; ++j)
                    out[((b0 + 4 * g + j) * T_STEPS + t) * OUT_C + c16] = acc[j];
            }
            if (wid == 0) {
                float xn[4];
                if (st == 0) {
                    k1 = acc;
#pragma unroll
                    for (int j = 0; j < 4; ++j) xn[j] = fmaf(0.5f * DT_F, k1[j], xb[j]);
                } else if (st == 1) {
                    k2 = acc;
#pragma unroll
                    for (int j = 0; j < 4; ++j) xn[j] = fmaf(0.5f * DT_F, k2[j], xb[j]);
                } else if (st == 2) {
                    k3 = acc;
#pragma unroll
                    for (int j = 0; j < 4; ++j) xn[j] = fmaf(DT_F, k3[j], xb[j]);
                } else {
                    k4 = acc;
#pragma unroll
                    for (int j = 0; j < 4; ++j) {
                        xb[j] = fmaf(DT_F / 6.0f,
                                     k1[j] + 2.0f * k2[j] + 2.0f * k3[j] + k4[j], xb[j]);
                        xn[j] = xb[j];
                    }
                }
                if (g < 2) {
#pragma unroll
                    for (int j = 0; j < 4; ++j) {
                        int row = 4 * g + j;
                        *(_Float16*)(lds + XY_OFF + row * 64 +
                                     ((2 * c16) ^ ((row & 3) << 4))) = (_Float16)xn[j];
                    }
                }
            }
            __syncthreads();                   // new x visible for next bias
        }
    }
}

// ---- value baseline MLP + log_std broadcast (unchanged) ----
__device__ __forceinline__ float fast_tanh(float a) {
    float e = __expf(2.0f * a);
    return 1.0f - 2.0f / (e + 1.0f);
}

__global__ __launch_bounds__(256) void mlp_kernel(
    const float* __restrict__ obs, const float* __restrict__ log_stds,
    const float* __restrict__ W1, const float* __restrict__ b1,
    const float* __restrict__ W2, const float* __restrict__ b2,
    const float* __restrict__ W3, const float* __restrict__ b3,
    float* __restrict__ out) {
    __shared__ float sW1[IN_D * H_D];
    __shared__ float sW2[H_D * H_D];
    __shared__ float sb1[H_D], sb2[H_D], sW3[H_D], sls[OUT_D];
    __shared__ float sb3;
    const int tid = threadIdx.x;
    for (int i = tid; i < IN_D * H_D; i += 256) sW1[i] = W1[i];
    for (int i = tid; i < H_D * H_D; i += 256) sW2[i] = W2[i];
    if (tid < H_D) { sb1[tid] = b1[tid]; sb2[tid] = b2[tid]; sW3[tid] = W3[tid]; }
    if (tid < OUT_D) sls[tid] = log_stds[tid];
    if (tid == 0) sb3 = b3[0];
    __syncthreads();

    const int bt = blockIdx.x * 256 + tid;
    if (bt >= B_TOT * T_STEPS) return;

    float o[IN_D];
#pragma unroll
    for (int i = 0; i < IN_D; ++i) o[i] = obs[bt * IN_D + i];

    float h1[H_D];
#pragma unroll
    for (int h = 0; h < H_D; ++h) {
        float a = sb1[h];
#pragma unroll
        for (int i = 0; i < IN_D; ++i) a = fmaf(o[i], sW1[i * H_D + h], a);
        h1[h] = fast_tanh(a);
    }
    float v = sb3;
#pragma unroll
    for (int h = 0; h < H_D; ++h) {
        float a = sb2[h];
#pragma unroll
        for (int i = 0; i < H_D; ++i) a = fmaf(h1[i], sW2[i * H_D + h], a);
        v = fmaf(fast_tanh(a), sW3[h], v);
    }

    float* o17 = out + bt * OUT_C;
#pragma unroll
    for (int q = 0; q < OUT_D; ++q) o17[OUT_D + q] = sls[q];
    o17[16] = v;
}

extern "C" void kernel_launch(void* const* d_in, const int* in_sizes, int n_in,
                              void* d_out, int out_size, void* d_ws, size_t ws_size,
                              hipStream_t stream) {
    const float* obs      = (const float*)d_in[0];
    const float* x0       = (const float*)d_in[1];
    const float* A_T      = (const float*)d_in[2];
    const float* Bw_T     = (const float*)d_in[3];
    const float* By_T     = (const float*)d_in[4];
    const float* Cv_T     = (const float*)d_in[5];
    const float* Dvw_T    = (const float*)d_in[6];
    const float* Dvy_T    = (const float*)d_in[7];
    const float* Cu_T     = (const float*)d_in[8];
    const float* Duw_T    = (const float*)d_in[9];
    const float* Duy_T    = (const float*)d_in[10];
    const float* log_stds = (const float*)d_in[11];
    const float* W1       = (const float*)d_in[12];
    const float* b1       = (const float*)d_in[13];
    const float* W2       = (const float*)d_in[14];
    const float* b2       = (const float*)d_in[15];
    const float* W3       = (const float*)d_in[16];
    const float* b3       = (const float*)d_in[17];
    float* out = (float*)d_out;

    rinn_fpi<<<dim3(B_TOT / RB), dim3(512), 0, stream>>>(
        obs, x0, A_T, Bw_T, By_T, Cv_T, Dvw_T, Dvy_T, Cu_T, Duw_T, Duy_T, out);
    mlp_kernel<<<dim3((B_TOT * T_STEPS + 255) / 256), dim3(256), 0, stream>>>(
        obs, log_stds, W1, b1, W2, b2, W3, b3, out);
}